// Round 1
// baseline (1874.440 us; speedup 1.0000x reference)
//
#include <hip/hip_runtime.h>
#include <cstdint>

// SelfMatchingLayer: B=32, L=512, H=256, fp32.
// Decomposition: attention/context/gates are h-independent -> parallel phase;
// only the two GRU scans are sequential (one block per (batch,dir), Whh held
// as packed fp16 in VGPRs, v_dot2_f32_f16 matvec, __syncthreads-only sync).

#define LL 512
#define HH 256
#define BBATCH 32

typedef _Float16 half2_t __attribute__((ext_vector_type(2)));

__device__ __forceinline__ float exp2f_fast(float x){
#if defined(__HIP_DEVICE_COMPILE__)
  return __builtin_amdgcn_exp2f(x);
#else
  return exp2f(x);
#endif
}
__device__ __forceinline__ float rcpf_fast(float x){
#if defined(__HIP_DEVICE_COMPILE__)
  return __builtin_amdgcn_rcpf(x);
#else
  return 1.0f/x;
#endif
}
// tanh(x) = 1 - 2/(1+e^{2x}); exp2-based, saturates correctly at +-inf args.
__device__ __forceinline__ float tanh_fast(float x){
  float e = exp2f_fast(x * 2.885390081777927f);   // 2*log2(e)
  return 1.0f - 2.0f * rcpf_fast(1.0f + e);
}
__device__ __forceinline__ float sigmoid_fast(float x){
  return rcpf_fast(1.0f + exp2f_fast(x * -1.4426950408889634f));
}

// ---------------- K1: Hq = P@wq^T + bq ; Pp = P@wp^T + bp ----------------
// 512 blocks x 32 rows; thread = output column j; P-tile in LDS (stride 260
// keeps float4 16B-aligned; broadcast reads are conflict-free).
__global__ __launch_bounds__(256) void k1_hq_pp(
    const float* __restrict__ P, const float* __restrict__ wq_w, const float* __restrict__ wq_b,
    const float* __restrict__ wp_w, const float* __restrict__ wp_b,
    float* __restrict__ HQ, float* __restrict__ PP)
{
  __shared__ float Pt[32*260];
  int tid = threadIdx.x;
  int r0 = blockIdx.x * 32;            // flat row (b*L + l)
  for (int i = 0; i < 32; i++)
    Pt[i*260 + tid] = P[(size_t)(r0+i)*HH + tid];
  __syncthreads();
  int j = tid;
  float accq[32], accp[32];
  #pragma unroll
  for (int i=0;i<32;i++){ accq[i]=0.f; accp[i]=0.f; }
  const float* wqr = wq_w + (size_t)j*HH;
  const float* wpr = wp_w + (size_t)j*HH;
  for (int k0 = 0; k0 < HH; k0 += 4) {
    float4 wq4 = *(const float4*)(wqr + k0);
    float4 wp4 = *(const float4*)(wpr + k0);
    #pragma unroll
    for (int i=0;i<32;i++){
      float4 p4 = *(const float4*)(&Pt[i*260 + k0]);
      accq[i] += p4.x*wq4.x + p4.y*wq4.y + p4.z*wq4.z + p4.w*wq4.w;
      accp[i] += p4.x*wp4.x + p4.y*wp4.y + p4.z*wp4.z + p4.w*wp4.w;
    }
  }
  float bq = wq_b[j], bp = wp_b[j];
  for (int i=0;i<32;i++){
    HQ[(size_t)(r0+i)*HH + j] = accq[i] + bq;
    PP[(size_t)(r0+i)*HH + j] = accp[i] + bp;
  }
}

// ---------------- K2: S[b,t,l] = sum_h ws[h]*tanh(Hq[b,l,h]+Pp[b,t,h]) ----
// (ws_b omitted: softmax-invariant constant.)
// block = (t-tile of 32, b); Pp tile resident, Hq streamed in 16-row chunks.
// stride 257 => 8 rows spaced 2 hit 8 distinct banks (conflict-free b32).
__global__ __launch_bounds__(256) void k2_scores(
    const float* __restrict__ HQ, const float* __restrict__ PP,
    const float* __restrict__ ws_w, float* __restrict__ S)
{
  __shared__ float Pp_t[32*257];
  __shared__ float Hq_c[16*257];
  __shared__ float wsl[256];
  int tid = threadIdx.x;
  int b = blockIdx.y;
  int t0 = blockIdx.x * 32;
  wsl[tid] = ws_w[tid];
  for (int i=0;i<32;i++)
    Pp_t[i*257 + tid] = PP[((size_t)b*LL + t0 + i)*HH + tid];
  int tt = tid >> 3, ls = tid & 7;
  for (int c = 0; c < 32; c++) {
    __syncthreads();                    // protect Hq_c reuse + first Pp use
    int l0 = c*16;
    for (int i=0;i<16;i++)
      Hq_c[i*257 + tid] = HQ[((size_t)b*LL + l0 + i)*HH + tid];
    __syncthreads();
    int la = ls*2, lb = la+1;
    float s0 = 0.f, s1 = 0.f;
    for (int h = 0; h < HH; h++) {
      float pq = Pp_t[tt*257 + h];
      float wv = wsl[h];
      s0 += wv * tanh_fast(Hq_c[la*257 + h] + pq);
      s1 += wv * tanh_fast(Hq_c[lb*257 + h] + pq);
    }
    S[((size_t)b*LL + t0 + tt)*LL + l0 + la] = s0;
    S[((size_t)b*LL + t0 + tt)*LL + l0 + lb] = s1;
  }
}

// ---------------- K3: softmax over l, in place; one wave per row ----------
__global__ __launch_bounds__(256) void k3_softmax(float* __restrict__ S)
{
  int wave = threadIdx.x >> 6, lane = threadIdx.x & 63;
  size_t row = (size_t)blockIdx.x*4 + wave;
  float* p = S + row*LL;
  float v[8];
  #pragma unroll
  for (int i=0;i<8;i++) v[i] = p[lane + 64*i];
  float m = v[0];
  #pragma unroll
  for (int i=1;i<8;i++) m = fmaxf(m, v[i]);
  #pragma unroll
  for (int off=32; off>=1; off>>=1) m = fmaxf(m, __shfl_xor(m, off, 64));
  float s = 0.f;
  #pragma unroll
  for (int i=0;i<8;i++){ v[i] = exp2f_fast((v[i]-m)*1.4426950408889634f); s += v[i]; }
  #pragma unroll
  for (int off=32; off>=1; off>>=1) s += __shfl_xor(s, off, 64);
  float inv = 1.0f / s;
  #pragma unroll
  for (int i=0;i<8;i++) p[lane + 64*i] = v[i]*inv;
}

// ---------------- K4: C[b,t,:] = attn[b,t,:] @ P[b,:,:] -------------------
// block = (t-tile of 32, b); full attn tile (32x512, 64KB) in LDS (broadcast
// reads, b128-aligned); thread = column j.
__global__ __launch_bounds__(256) void k4_context(
    const float* __restrict__ S, const float* __restrict__ P, float* __restrict__ C)
{
  __shared__ float A[32*512];
  int tid = threadIdx.x;
  int b = blockIdx.y;
  int t0 = blockIdx.x*32;
  for (int i=0;i<32;i++){
    A[i*512 + tid]       = S[((size_t)b*LL + t0+i)*LL + tid];
    A[i*512 + 256 + tid] = S[((size_t)b*LL + t0+i)*LL + 256 + tid];
  }
  __syncthreads();
  int j = tid;
  float acc[32];
  #pragma unroll
  for (int i=0;i<32;i++) acc[i]=0.f;
  for (int l0=0; l0<LL; l0+=4){
    float p0 = P[((size_t)b*LL + l0+0)*HH + j];
    float p1 = P[((size_t)b*LL + l0+1)*HH + j];
    float p2 = P[((size_t)b*LL + l0+2)*HH + j];
    float p3 = P[((size_t)b*LL + l0+3)*HH + j];
    #pragma unroll
    for (int t=0;t<32;t++){
      float4 a4 = *(const float4*)(&A[t*512 + l0]);
      acc[t] += a4.x*p0 + a4.y*p1 + a4.z*p2 + a4.w*p3;
    }
  }
  for (int t=0;t<32;t++)
    C[((size_t)b*LL + t0+t)*HH + j] = acc[t];
}

// ---------------- K5: Cg = sigmoid(P@wgp^T + C@wgc^T + bg) * C ------------
__global__ __launch_bounds__(256) void k5_gate(
    const float* __restrict__ P, const float* __restrict__ C,
    const float* __restrict__ wg_w, const float* __restrict__ wg_b,
    float* __restrict__ CG)
{
  __shared__ float Pt[32*260];
  __shared__ float Ct[32*260];
  int tid = threadIdx.x;
  int r0 = blockIdx.x*32;
  for (int i=0;i<32;i++){
    Pt[i*260 + tid] = P[(size_t)(r0+i)*HH + tid];
    Ct[i*260 + tid] = C[(size_t)(r0+i)*HH + tid];
  }
  __syncthreads();
  int j = tid;
  float acc[32];
  #pragma unroll
  for (int i=0;i<32;i++) acc[i]=0.f;
  const float* wgp = wg_w + (size_t)j*(2*HH);   // wg_w[j, 0:256] -> p part
  const float* wgc = wgp + HH;                  // wg_w[j, 256:512] -> c part
  for (int k0=0;k0<HH;k0+=4){
    float4 wp4 = *(const float4*)(wgp + k0);
    float4 wc4 = *(const float4*)(wgc + k0);
    #pragma unroll
    for (int i=0;i<32;i++){
      float4 pv = *(const float4*)(&Pt[i*260+k0]);
      float4 cv = *(const float4*)(&Ct[i*260+k0]);
      acc[i] += pv.x*wp4.x + pv.y*wp4.y + pv.z*wp4.z + pv.w*wp4.w
              + cv.x*wc4.x + cv.y*wc4.y + cv.z*wc4.z + cv.w*wc4.w;
    }
  }
  float bg = wg_b[j];
  for (int i=0;i<32;i++){
    float g = sigmoid_fast(acc[i] + bg);
    CG[(size_t)(r0+i)*HH + j] = g * Ct[i*260 + j];
  }
}

// ---------------- K6: GI_{l,r} = Cg @ Wih^T + bih (both directions) -------
// thread = unit j, computes rows j (r), j+256 (z), j+512 (n).
__global__ __launch_bounds__(256) void k6_gi(
    const float* __restrict__ CG,
    const float* __restrict__ Wih_l, const float* __restrict__ bih_l,
    const float* __restrict__ Wih_r, const float* __restrict__ bih_r,
    float* __restrict__ GIL, float* __restrict__ GIR)
{
  __shared__ float Xt[32*260];
  int tid = threadIdx.x;
  int r0 = blockIdx.x*32;
  int dir = blockIdx.y;
  const float* Wih = dir ? Wih_r : Wih_l;
  const float* bih = dir ? bih_r : bih_l;
  float* GI = dir ? GIR : GIL;
  for (int i=0;i<32;i++)
    Xt[i*260 + tid] = CG[(size_t)(r0+i)*HH + tid];
  __syncthreads();
  int j = tid;
  float ar[32], az[32], an[32];
  #pragma unroll
  for (int i=0;i<32;i++){ ar[i]=0.f; az[i]=0.f; an[i]=0.f; }
  const float* wr = Wih + (size_t)j*HH;
  const float* wz = Wih + (size_t)(j+256)*HH;
  const float* wn = Wih + (size_t)(j+512)*HH;
  for (int k0=0;k0<HH;k0+=4){
    float4 w_r = *(const float4*)(wr+k0);
    float4 w_z = *(const float4*)(wz+k0);
    float4 w_n = *(const float4*)(wn+k0);
    #pragma unroll
    for (int i=0;i<32;i++){
      float4 xv = *(const float4*)(&Xt[i*260+k0]);
      ar[i] += xv.x*w_r.x + xv.y*w_r.y + xv.z*w_r.z + xv.w*w_r.w;
      az[i] += xv.x*w_z.x + xv.y*w_z.y + xv.z*w_z.z + xv.w*w_z.w;
      an[i] += xv.x*w_n.x + xv.y*w_n.y + xv.z*w_n.z + xv.w*w_n.w;
    }
  }
  float br = bih[j], bz = bih[j+256], bn = bih[j+512];
  for (int i=0;i<32;i++){
    size_t base = (size_t)(r0+i)*768;
    GI[base + j]       = ar[i] + br;
    GI[base + j + 256] = az[i] + bz;
    GI[base + j + 512] = an[i] + bn;
  }
}

// ---------------- K7: the two GRU scans ----------------------------------
// One block per (b, dir): 64 blocks x 768 threads (12 waves, 3/SIMD).
// Whh row per thread packed fp16 in 128 VGPRs; h as fp16 in LDS (broadcast
// b128 reads); gi prefetched one step ahead; h carry stays fp32 in-register.
#if defined(__HIP_DEVICE_COMPILE__) && __has_builtin(__builtin_amdgcn_fdot2)
#define USE_FDOT2 1
#endif

__global__ __launch_bounds__(768, 3) void k7_scan(
    const float* __restrict__ GIL, const float* __restrict__ GIR,
    const float* __restrict__ Whh_l, const float* __restrict__ bhh_l,
    const float* __restrict__ Whh_r, const float* __restrict__ bhh_r,
    float* __restrict__ out)
{
  int b   = blockIdx.x >> 1;
  int dir = blockIdx.x & 1;
  int row = threadIdx.x;                 // 0..767 = Whh row (r|z|n blocks)
  const float* GI  = dir ? GIR : GIL;
  const float* Whh = dir ? Whh_r : Whh_l;
  const float* bhh = dir ? bhh_r : bhh_l;

  unsigned int w[128];                   // 256 fp16 weights packed
  {
    const float* wrp = Whh + (size_t)row*HH;
    #pragma unroll
    for (int p=0;p<128;p++){
      float2 f = ((const float2*)wrp)[p];
      half2_t hw = { (_Float16)f.x, (_Float16)f.y };
      w[p] = __builtin_bit_cast(unsigned int, hw);
    }
  }
  float bias = bhh[row];

  __shared__ float gh[768];
  __shared__ __align__(16) unsigned short hs[256];  // fp16 bits of h
  if (row < 256) hs[row] = 0;
  __syncthreads();

  float hprev = 0.f;
  float gir=0.f, giz=0.f, gin=0.f;
  if (row < 256){
    const float* g = GI + ((size_t)b*LL + (dir ? (LL-1) : 0))*768;
    gir = g[row]; giz = g[row+256]; gin = g[row+512];
  }

  for (int s=0; s<LL; s++){
    int t = dir ? (LL-1-s) : s;
    float a0=0.f, a1=0.f, a2=0.f, a3=0.f;
    #pragma unroll
    for (int p=0;p<128;p+=4){
      uint4 hv = *((const uint4*)(hs + 2*p));
#ifdef USE_FDOT2
      a0 = __builtin_amdgcn_fdot2(__builtin_bit_cast(half2_t, w[p+0]), __builtin_bit_cast(half2_t, hv.x), a0, false);
      a1 = __builtin_amdgcn_fdot2(__builtin_bit_cast(half2_t, w[p+1]), __builtin_bit_cast(half2_t, hv.y), a1, false);
      a2 = __builtin_amdgcn_fdot2(__builtin_bit_cast(half2_t, w[p+2]), __builtin_bit_cast(half2_t, hv.z), a2, false);
      a3 = __builtin_amdgcn_fdot2(__builtin_bit_cast(half2_t, w[p+3]), __builtin_bit_cast(half2_t, hv.w), a3, false);
#else
      {
        half2_t wv0=__builtin_bit_cast(half2_t,w[p+0]), hv0=__builtin_bit_cast(half2_t,hv.x);
        half2_t wv1=__builtin_bit_cast(half2_t,w[p+1]), hv1=__builtin_bit_cast(half2_t,hv.y);
        half2_t wv2=__builtin_bit_cast(half2_t,w[p+2]), hv2=__builtin_bit_cast(half2_t,hv.z);
        half2_t wv3=__builtin_bit_cast(half2_t,w[p+3]), hv3=__builtin_bit_cast(half2_t,hv.w);
        a0 += (float)wv0.x*(float)hv0.x + (float)wv0.y*(float)hv0.y;
        a1 += (float)wv1.x*(float)hv1.x + (float)wv1.y*(float)hv1.y;
        a2 += (float)wv2.x*(float)hv2.x + (float)wv2.y*(float)hv2.y;
        a3 += (float)wv3.x*(float)hv3.x + (float)wv3.y*(float)hv3.y;
      }
#endif
    }
    gh[row] = bias + ((a0+a1)+(a2+a3));
    // prefetch next step's gi while the barrier drains
    float ngr=0.f, ngz=0.f, ngn=0.f;
    if (row < 256 && s+1 < LL){
      int tn = dir ? (LL-2-s) : (s+1);
      const float* g = GI + ((size_t)b*LL + tn)*768;
      ngr = g[row]; ngz = g[row+256]; ngn = g[row+512];
    }
    __syncthreads();
    if (row < 256){
      float r = sigmoid_fast(gir + gh[row]);
      float z = sigmoid_fast(giz + gh[row+256]);
      float n = tanh_fast(gin + r*gh[row+512]);
      float hn = z*(hprev - n) + n;
      hprev = hn;
      out[((size_t)b*LL + t)*(2*HH) + dir*HH + row] = hn;
      hs[row] = __builtin_bit_cast(unsigned short, (_Float16)hn);
      gir=ngr; giz=ngz; gin=ngn;
    }
    __syncthreads();
  }
}

extern "C" void kernel_launch(void* const* d_in, const int* in_sizes, int n_in,
                              void* d_out, int out_size, void* d_ws, size_t ws_size,
                              hipStream_t stream)
{
  const float* P    = (const float*)d_in[0];
  const float* wq_w = (const float*)d_in[1];
  const float* wq_b = (const float*)d_in[2];
  const float* wp_w = (const float*)d_in[3];
  const float* wp_b = (const float*)d_in[4];
  const float* ws_w = (const float*)d_in[5];
  // d_in[6] = ws_b: constant shift, cancels in softmax -> unused
  const float* wg_w = (const float*)d_in[7];
  const float* wg_b = (const float*)d_in[8];
  const float* Wih_l= (const float*)d_in[9];
  const float* Whh_l= (const float*)d_in[10];
  const float* bih_l= (const float*)d_in[11];
  const float* bhh_l= (const float*)d_in[12];
  const float* Wih_r= (const float*)d_in[13];
  const float* Whh_r= (const float*)d_in[14];
  const float* bih_r= (const float*)d_in[15];
  const float* bhh_r= (const float*)d_in[16];

  float* ws  = (float*)d_ws;
  // Workspace layout (floats). GIL aliases HQ/PP/S-front, all dead by K6.
  // Total: 37,748,736 floats = 151 MB.
  float* HQ  = ws;                    // 4,194,304
  float* PP  = ws + 4194304;          // 4,194,304
  float* S   = ws + 8388608;          // 8,388,608
  float* C   = ws + 16777216;         // 4,194,304
  float* CG  = ws + 20971520;         // 4,194,304
  float* GIR = ws + 25165824;         // 12,582,912
  float* GIL = ws;                    // 12,582,912 (alias)
  float* out = (float*)d_out;

  k1_hq_pp  <<<512,          256, 0, stream>>>(P, wq_w, wq_b, wp_w, wp_b, HQ, PP);
  k2_scores <<<dim3(16,32),  256, 0, stream>>>(HQ, PP, ws_w, S);
  k3_softmax<<<4096,         256, 0, stream>>>(S);
  k4_context<<<dim3(16,32),  256, 0, stream>>>(S, P, C);
  k5_gate   <<<512,          256, 0, stream>>>(P, C, wg_w, wg_b, CG);
  k6_gi     <<<dim3(512,2),  256, 0, stream>>>(CG, Wih_l, bih_l, Wih_r, bih_r, GIL, GIR);
  k7_scan   <<<64,           768, 0, stream>>>(GIL, GIR, Whh_l, bhh_l, Whh_r, bhh_r, out);
}